// Round 1
// baseline (12293.526 us; speedup 1.0000x reference)
//
#include <hip/hip_runtime.h>
#include <math.h>

#define B 8
#define NS 4096
#define NC 256
#define TH 8
#define TP 24
#define DIN 28
#define DM 27
#define G 64
#define H 64
#define DGRU 92
#define NG3 192

__device__ __forceinline__ float sigmoidf_(float x) { return 1.0f / (1.0f + expf(-x)); }

// ---------------- setup: CSR construction ----------------
// element (r, n) of logical matrix at M[r*rs + n*cs]
__global__ void count_kernel(const float* __restrict__ M, int C, size_t rs, size_t cs,
                             int excl_diag, int* __restrict__ cnt1, float* __restrict__ dinv) {
  int r = blockIdx.x;
  int c = 0;
  for (int n = threadIdx.x; n < C; n += blockDim.x) {
    float v = M[(size_t)r * rs + (size_t)n * cs];
    if (v != 0.0f && !(excl_diag && n == r)) c++;
  }
  __shared__ int sh[256];
  sh[threadIdx.x] = c;
  __syncthreads();
  for (int s = 128; s > 0; s >>= 1) {
    if (threadIdx.x < s) sh[threadIdx.x] += sh[threadIdx.x + s];
    __syncthreads();
  }
  if (threadIdx.x == 0) {
    cnt1[r + 1] = sh[0];
    if (dinv) dinv[r] = (sh[0] > 0) ? rsqrtf((float)sh[0]) : 0.0f;
  }
}

__global__ void scan_kernel(int* __restrict__ ptr, int R) {
  __shared__ int sh[4096];
  for (int i = threadIdx.x; i < R; i += blockDim.x) sh[i] = ptr[i + 1];
  __syncthreads();
  if (threadIdx.x == 0) {
    int run = 0;
    for (int i = 0; i < R; i++) { run += sh[i]; sh[i] = run; }
    ptr[0] = 0;
  }
  __syncthreads();
  for (int i = threadIdx.x; i < R; i += blockDim.x) ptr[i + 1] = sh[i];
}

// one wave (64 threads) per row; deterministic ballot compaction
__global__ void fill_kernel(const float* __restrict__ M, int C, size_t rs, size_t cs,
                            int excl_diag, const int* __restrict__ ptr,
                            const float* __restrict__ dinv,
                            int* __restrict__ cols, float* __restrict__ vals) {
  int r = blockIdx.x;
  int lane = threadIdx.x;
  int base = ptr[r];
  float dr = dinv ? dinv[r] : 1.0f;
  for (int n0 = 0; n0 < C; n0 += 64) {
    int n = n0 + lane;
    bool flag = false;
    float v = 0.0f;
    if (n < C) {
      v = M[(size_t)r * rs + (size_t)n * cs];
      flag = (v != 0.0f) && !(excl_diag && n == r);
    }
    unsigned long long mask = __ballot(flag);
    if (flag) {
      int pos = base + (int)__popcll(mask & ((1ull << lane) - 1ull));
      cols[pos] = n;
      vals[pos] = dinv ? (-dr * dinv[n]) : v;
    }
    base += (int)__popcll(mask);
  }
}

// x source: f==0 -> x_hist (hist) or x_prev (pred); f>=1 -> features[t_f][f-1]
__device__ __forceinline__ float xsrc_val(const float* __restrict__ xh,
                                          const float* __restrict__ feat,
                                          const float* __restrict__ xprev,
                                          int is_hist, int t, int N, int b, int n, int f) {
  if (f == 0) {
    return is_hist ? xh[((size_t)b * TH + t) * N + n] : xprev[(size_t)b * N + n];
  }
  int tf = is_hist ? (t + 1) : (TH + t);
  return feat[(((size_t)b * 32 + tf) * N + n) * DM + (f - 1)];
}

// ---------------- cheb conv (K=2) + sigmoid, station + city in one launch ----------------
#define CHEB_NB 16
__global__ void cheb_kernel(
    const int* __restrict__ ptr_s, const int* __restrict__ cols_s, const float* __restrict__ vals_s,
    const float* __restrict__ xh_s, const float* __restrict__ feat_s, const float* __restrict__ xprev_s,
    const float* __restrict__ W_s, const float* __restrict__ b_s, float* __restrict__ out_s,
    const int* __restrict__ ptr_c, const int* __restrict__ cols_c, const float* __restrict__ vals_c,
    const float* __restrict__ xh_c, const float* __restrict__ feat_c, const float* __restrict__ xprev_c,
    const float* __restrict__ W_c, const float* __restrict__ b_c, float* __restrict__ out_c,
    int is_hist, int t, int nblk_s) {
  __shared__ float xa[CHEB_NB][DIN];
  __shared__ float lx[CHEB_NB][DIN];
  int bid = blockIdx.x;
  int N;
  const int *ptr, *cols;
  const float *vals, *xh, *feat, *xprev, *W, *bias;
  float* out;
  if (bid < nblk_s) {
    N = NS; ptr = ptr_s; cols = cols_s; vals = vals_s;
    xh = xh_s; feat = feat_s; xprev = xprev_s; W = W_s; bias = b_s; out = out_s;
  } else {
    bid -= nblk_s;
    N = NC; ptr = ptr_c; cols = cols_c; vals = vals_c;
    xh = xh_c; feat = feat_c; xprev = xprev_c; W = W_c; bias = b_c; out = out_c;
  }
  int per_b = N / CHEB_NB;
  int b = bid / per_b;
  int node0 = (bid % per_b) * CHEB_NB;

  for (int q = threadIdx.x; q < CHEB_NB * DIN; q += blockDim.x) {
    int i = q / DIN, f = q % DIN;
    xa[i][f] = xsrc_val(xh, feat, xprev, is_hist, t, N, b, node0 + i, f);
  }
  for (int q = threadIdx.x; q < CHEB_NB * DIN; q += blockDim.x) {
    int i = q / DIN, f = q % DIN;
    int m = node0 + i;
    float acc = 0.0f;
    int e0 = ptr[m], e1 = ptr[m + 1];
    for (int e = e0; e < e1; e++) {
      acc += vals[e] * xsrc_val(xh, feat, xprev, is_hist, t, N, b, cols[e], f);
    }
    lx[i][f] = acc;
  }
  __syncthreads();
  for (int o = threadIdx.x; o < CHEB_NB * G; o += blockDim.x) {
    int i = o >> 6, g = o & 63;
    float acc = bias[g];
#pragma unroll 4
    for (int f = 0; f < DIN; f++) {
      acc += xa[i][f] * W[f * G + g] + lx[i][f] * W[DIN * G + f * G + g];
    }
    out[((size_t)b * N + node0 + i) * G + g] = sigmoidf_(acc);
  }
}

// ---------------- fuse: station += (afc@xcg)@c2s_w + b ; city += (afc^T@xg)@s2c_w + b ----------------
#define FUSE_NB 16
__global__ void fuse_kernel(
    const int* __restrict__ ptr_f, const int* __restrict__ cols_f, const float* __restrict__ vals_f,
    const int* __restrict__ ptr_fT, const int* __restrict__ cols_fT, const float* __restrict__ vals_fT,
    const float* __restrict__ xg_s, const float* __restrict__ xg_c,
    const float* __restrict__ c2s_w, const float* __restrict__ c2s_b,
    const float* __restrict__ s2c_w, const float* __restrict__ s2c_b,
    float* __restrict__ out_s, float* __restrict__ out_c, int nblk_s) {
  __shared__ float tmp[FUSE_NB][G];
  int bid = blockIdx.x;
  int N, srcN;
  const int *ptr, *cols;
  const float *valsv, *src, *base_in, *Wm, *bb;
  float* out;
  if (bid < nblk_s) {
    N = NS; srcN = NC; ptr = ptr_f; cols = cols_f; valsv = vals_f;
    src = xg_c; base_in = xg_s; Wm = c2s_w; bb = c2s_b; out = out_s;
  } else {
    bid -= nblk_s;
    N = NC; srcN = NS; ptr = ptr_fT; cols = cols_fT; valsv = vals_fT;
    src = xg_s; base_in = xg_c; Wm = s2c_w; bb = s2c_b; out = out_c;
  }
  int per_b = N / FUSE_NB;
  int b = bid / per_b;
  int node0 = (bid % per_b) * FUSE_NB;
  for (int o = threadIdx.x; o < FUSE_NB * G; o += blockDim.x) {
    int i = o >> 6, g = o & 63;
    int m = node0 + i;
    float acc = 0.0f;
    int e0 = ptr[m], e1 = ptr[m + 1];
    for (int e = e0; e < e1; e++) {
      acc += valsv[e] * src[((size_t)b * srcN + cols[e]) * G + g];
    }
    tmp[i][g] = acc;
  }
  __syncthreads();
  for (int o = threadIdx.x; o < FUSE_NB * G; o += blockDim.x) {
    int i = o >> 6, g = o & 63;
    float acc = bb[g];
#pragma unroll 4
    for (int f = 0; f < G; f++) acc += tmp[i][f] * Wm[f * G + g];
    size_t off = ((size_t)b * N + node0 + i) * G + g;
    out[off] = base_in[off] + acc;
  }
}

// ---------------- GRU (+ fc head in pred mode), station + city in one launch ----------------
#define GRU_NB 32
__global__ __launch_bounds__(256) void gru_kernel(
    const float* __restrict__ xh_s, const float* __restrict__ feat_s,
    const float* __restrict__ xprev_s, const float* __restrict__ xg2_s,
    const float* __restrict__ wi_s, const float* __restrict__ wh_s,
    const float* __restrict__ bi_s, const float* __restrict__ bh_s,
    float* __restrict__ h_s, const float* __restrict__ fcw_s, const float* __restrict__ fcb_s,
    const float* __restrict__ xh_c, const float* __restrict__ feat_c,
    const float* __restrict__ xprev_c, const float* __restrict__ xg2_c,
    const float* __restrict__ wi_c, const float* __restrict__ wh_c,
    const float* __restrict__ bi_c, const float* __restrict__ bh_c,
    float* __restrict__ h_c, const float* __restrict__ fcw_c, const float* __restrict__ fcb_c,
    float* __restrict__ yout, float* __restrict__ xpo_s, float* __restrict__ xpo_c,
    int is_pred, int t, int idx, int nblk_s) {
  __shared__ float xcat[GRU_NB][DGRU];      // stride 92: banks i*28%32 distinct for i 0..7
  __shared__ float hld[GRU_NB][H + 4];      // stride 68: avoids 8-way bank conflict
  __shared__ float gates[GRU_NB][260];      // [0:128)=r,z sums  [128:192)=xn  [192:256)=hc
  int bid = blockIdx.x;
  int N;
  const float *xh, *feat, *xprev, *xg2, *wi, *wh, *bi, *bh, *fcw, *fcb;
  float *hg, *xpo;
  size_t yoff;
  if (bid < nblk_s) {
    N = NS; xh = xh_s; feat = feat_s; xprev = xprev_s; xg2 = xg2_s;
    wi = wi_s; wh = wh_s; bi = bi_s; bh = bh_s; hg = h_s; fcw = fcw_s; fcb = fcb_s;
    xpo = xpo_s; yoff = 0;
  } else {
    bid -= nblk_s;
    N = NC; xh = xh_c; feat = feat_c; xprev = xprev_c; xg2 = xg2_c;
    wi = wi_c; wh = wh_c; bi = bi_c; bh = bh_c; hg = h_c; fcw = fcw_c; fcb = fcb_c;
    xpo = xpo_c; yoff = (size_t)B * TP * NS;
  }
  int per_b = N / GRU_NB;
  int b = bid / per_b;
  int node0 = (bid % per_b) * GRU_NB;
  int is_hist = !is_pred;

  for (int q = threadIdx.x; q < GRU_NB * DGRU; q += blockDim.x) {
    int i = q / DGRU, d = q % DGRU;
    int m = node0 + i;
    float v;
    if (d < DIN) v = xsrc_val(xh, feat, xprev, is_hist, t, N, b, m, d);
    else v = xg2[((size_t)b * N + m) * G + (d - DIN)];
    xcat[i][d] = v;
  }
  for (int q = threadIdx.x; q < GRU_NB * H; q += blockDim.x) {
    int i = q >> 6, j = q & 63;
    hld[i][j] = hg[((size_t)b * N + node0 + i) * H + j];
  }
  __syncthreads();

  int i = threadIdx.x >> 3;
  int sub = threadIdx.x & 7;
  int j0 = sub * 24;
  float4 acc[6];
  {
    const float4* bi4 = (const float4*)(bi + j0);
#pragma unroll
    for (int q = 0; q < 6; q++) acc[q] = bi4[q];
    const float* wibase = wi + j0;
    for (int d = 0; d < DGRU; d++) {
      float a = xcat[i][d];
      const float4* w4 = (const float4*)(wibase + d * NG3);
#pragma unroll
      for (int q = 0; q < 6; q++) {
        float4 w = w4[q];
        acc[q].x += a * w.x; acc[q].y += a * w.y; acc[q].z += a * w.z; acc[q].w += a * w.w;
      }
    }
    float4* gx = (float4*)(&gates[i][j0]);
#pragma unroll
    for (int q = 0; q < 6; q++) gx[q] = acc[q];
  }
  {
    const float4* bh4 = (const float4*)(bh + j0);
#pragma unroll
    for (int q = 0; q < 6; q++) acc[q] = bh4[q];
    const float* whbase = wh + j0;
    for (int d = 0; d < H; d++) {
      float a = hld[i][d];
      const float4* w4 = (const float4*)(whbase + d * NG3);
#pragma unroll
      for (int q = 0; q < 6; q++) {
        float4 w = w4[q];
        acc[q].x += a * w.x; acc[q].y += a * w.y; acc[q].z += a * w.z; acc[q].w += a * w.w;
      }
    }
#pragma unroll
    for (int q = 0; q < 6; q++) {
      float vv[4] = {acc[q].x, acc[q].y, acc[q].z, acc[q].w};
#pragma unroll
      for (int k = 0; k < 4; k++) {
        int j = j0 + q * 4 + k;
        if (j < 128) gates[i][j] += vv[k];   // same thread wrote it: no race
        else gates[i][j + 64] = vv[k];       // hc region at 192..255
      }
    }
  }
  __syncthreads();

  for (int q = threadIdx.x; q < GRU_NB * H; q += blockDim.x) {
    int ii = q >> 6, j = q & 63;
    float r = sigmoidf_(gates[ii][j]);
    float z = sigmoidf_(gates[ii][64 + j]);
    float xn = gates[ii][128 + j];
    float hc = gates[ii][192 + j];
    float nn = tanhf(xn + r * hc);
    float hold = hld[ii][j];
    float hnew = (1.0f - z) * nn + z * hold;
    int interval = 1 << (j >> 4);            // 1,2,4,8 per 16-wide group
    float hout = ((idx & (interval - 1)) == 0) ? hnew : hold;
    hg[((size_t)b * N + node0 + ii) * H + j] = hout;
    hld[ii][j] = hout;
  }
  if (is_pred) {
    __syncthreads();
    if (threadIdx.x < GRU_NB) {
      int ii = threadIdx.x;
      float acc2 = fcb[0];
#pragma unroll 8
      for (int j = 0; j < H; j++) acc2 += hld[ii][j] * fcw[j];
      int m = node0 + ii;
      yout[yoff + ((size_t)b * TP + t) * N + m] = acc2;
      xpo[(size_t)b * N + m] = acc2;
    }
  }
}

__global__ void xprev_init_kernel(const float* __restrict__ xh_s, const float* __restrict__ xh_c,
                                  float* __restrict__ xp_s, float* __restrict__ xp_c) {
  int i = blockIdx.x * blockDim.x + threadIdx.x;
  if (i < B * NS) {
    int b = i / NS, m = i % NS;
    xp_s[i] = xh_s[((size_t)b * TH + (TH - 1)) * NS + m];
  } else {
    int q = i - B * NS;
    if (q < B * NC) {
      int b = q / NC, c = q % NC;
      xp_c[q] = xh_c[((size_t)b * TH + (TH - 1)) * NC + c];
    }
  }
}

extern "C" void kernel_launch(void* const* d_in, const int* in_sizes, int n_in,
                              void* d_out, int out_size, void* d_ws, size_t ws_size,
                              hipStream_t stream) {
  const float* x_hist     = (const float*)d_in[0];
  const float* features   = (const float*)d_in[1];
  const float* c_x_hist   = (const float*)d_in[2];
  const float* c_features = (const float*)d_in[3];
  const float* adj_sta    = (const float*)d_in[4];
  const float* adj_city   = (const float*)d_in[5];
  const float* afc        = (const float*)d_in[6];
  const float* conv_w     = (const float*)d_in[7];
  const float* conv_b     = (const float*)d_in[8];
  const float* c_conv_w   = (const float*)d_in[9];
  const float* c_conv_b   = (const float*)d_in[10];
  const float* gru_wi     = (const float*)d_in[11];
  const float* gru_wh     = (const float*)d_in[12];
  const float* gru_bi     = (const float*)d_in[13];
  const float* gru_bh     = (const float*)d_in[14];
  const float* c_gru_wi   = (const float*)d_in[15];
  const float* c_gru_wh   = (const float*)d_in[16];
  const float* c_gru_bi   = (const float*)d_in[17];
  const float* c_gru_bh   = (const float*)d_in[18];
  const float* fc_w       = (const float*)d_in[19];
  const float* fc_b       = (const float*)d_in[20];
  const float* c_fc_w     = (const float*)d_in[21];
  const float* c_fc_b     = (const float*)d_in[22];
  const float* c2s_w      = (const float*)d_in[23];
  const float* c2s_b      = (const float*)d_in[24];
  const float* s2c_w      = (const float*)d_in[25];
  const float* s2c_b      = (const float*)d_in[26];
  float* out = (float*)d_out;

  char* wp = (char*)d_ws;
  auto alloc = [&](size_t bytes) -> char* {
    char* p = wp;
    wp += (bytes + 255) & ~(size_t)255;
    return p;
  };
  const int CAP_S = 524288, CAP_C = 65536, CAP_F = 131072;
  float* dinv_s = (float*)alloc(NS * 4);
  float* dinv_c = (float*)alloc(NC * 4);
  int* ptr_s  = (int*)alloc((NS + 1) * 4);
  int* ptr_c  = (int*)alloc((NC + 1) * 4);
  int* ptr_f  = (int*)alloc((NS + 1) * 4);
  int* ptr_fT = (int*)alloc((NC + 1) * 4);
  int* cols_s = (int*)alloc((size_t)CAP_S * 4); float* vals_s = (float*)alloc((size_t)CAP_S * 4);
  int* cols_c = (int*)alloc((size_t)CAP_C * 4); float* vals_c = (float*)alloc((size_t)CAP_C * 4);
  int* cols_f = (int*)alloc((size_t)CAP_F * 4); float* vals_f = (float*)alloc((size_t)CAP_F * 4);
  int* cols_fT = (int*)alloc((size_t)CAP_F * 4); float* vals_fT = (float*)alloc((size_t)CAP_F * 4);
  float* xg_s  = (float*)alloc((size_t)B * NS * G * 4);
  float* xg2_s = (float*)alloc((size_t)B * NS * G * 4);
  float* xg_c  = (float*)alloc((size_t)B * NC * G * 4);
  float* xg2_c = (float*)alloc((size_t)B * NC * G * 4);
  float* h_s = (float*)alloc((size_t)B * NS * H * 4);
  float* h_c = (float*)alloc((size_t)B * NC * H * 4);
  float* xp_s = (float*)alloc((size_t)B * NS * 4);
  float* xp_c = (float*)alloc((size_t)B * NC * 4);

  hipMemsetAsync(h_s, 0, (size_t)B * NS * H * 4, stream);
  hipMemsetAsync(h_c, 0, (size_t)B * NC * H * 4, stream);

  // CSR builds: L_s, L_c (diag-excluded, normalized), afc (rows=stations), afc^T (rows=cities)
  count_kernel<<<NS, 256, 0, stream>>>(adj_sta, NS, NS, 1, 1, ptr_s, dinv_s);
  count_kernel<<<NC, 256, 0, stream>>>(adj_city, NC, NC, 1, 1, ptr_c, dinv_c);
  count_kernel<<<NS, 256, 0, stream>>>(afc, NC, NC, 1, 0, ptr_f, nullptr);
  count_kernel<<<NC, 256, 0, stream>>>(afc, NS, 1, NC, 0, ptr_fT, nullptr);
  scan_kernel<<<1, 256, 0, stream>>>(ptr_s, NS);
  scan_kernel<<<1, 256, 0, stream>>>(ptr_c, NC);
  scan_kernel<<<1, 256, 0, stream>>>(ptr_f, NS);
  scan_kernel<<<1, 256, 0, stream>>>(ptr_fT, NC);
  fill_kernel<<<NS, 64, 0, stream>>>(adj_sta, NS, NS, 1, 1, ptr_s, dinv_s, cols_s, vals_s);
  fill_kernel<<<NC, 64, 0, stream>>>(adj_city, NC, NC, 1, 1, ptr_c, dinv_c, cols_c, vals_c);
  fill_kernel<<<NS, 64, 0, stream>>>(afc, NC, NC, 1, 0, ptr_f, nullptr, cols_f, vals_f);
  fill_kernel<<<NC, 64, 0, stream>>>(afc, NS, 1, NC, 0, ptr_fT, nullptr, cols_fT, vals_fT);

  int cheb_nblk_s = B * (NS / CHEB_NB);
  int cheb_grid = cheb_nblk_s + B * (NC / CHEB_NB);
  int gru_nblk_s = B * (NS / GRU_NB);
  int gru_grid = gru_nblk_s + B * (NC / GRU_NB);

  // history: 7 steps, idx = 1..7
  for (int t = 0; t < TH - 1; t++) {
    cheb_kernel<<<cheb_grid, 256, 0, stream>>>(
        ptr_s, cols_s, vals_s, x_hist, features, xp_s, conv_w, conv_b, xg_s,
        ptr_c, cols_c, vals_c, c_x_hist, c_features, xp_c, c_conv_w, c_conv_b, xg_c,
        1, t, cheb_nblk_s);
    fuse_kernel<<<cheb_grid, 256, 0, stream>>>(
        ptr_f, cols_f, vals_f, ptr_fT, cols_fT, vals_fT,
        xg_s, xg_c, c2s_w, c2s_b, s2c_w, s2c_b, xg2_s, xg2_c, cheb_nblk_s);
    gru_kernel<<<gru_grid, 256, 0, stream>>>(
        x_hist, features, xp_s, xg2_s, gru_wi, gru_wh, gru_bi, gru_bh, h_s, fc_w, fc_b,
        c_x_hist, c_features, xp_c, xg2_c, c_gru_wi, c_gru_wh, c_gru_bi, c_gru_bh, h_c, c_fc_w, c_fc_b,
        out, xp_s, xp_c, 0, t, t + 1, gru_nblk_s);
  }

  xprev_init_kernel<<<(B * NS + B * NC + 255) / 256, 256, 0, stream>>>(x_hist, c_x_hist, xp_s, xp_c);

  // prediction: 24 autoregressive steps, idx = 8..31
  for (int t = 0; t < TP; t++) {
    cheb_kernel<<<cheb_grid, 256, 0, stream>>>(
        ptr_s, cols_s, vals_s, x_hist, features, xp_s, conv_w, conv_b, xg_s,
        ptr_c, cols_c, vals_c, c_x_hist, c_features, xp_c, c_conv_w, c_conv_b, xg_c,
        0, t, cheb_nblk_s);
    fuse_kernel<<<cheb_grid, 256, 0, stream>>>(
        ptr_f, cols_f, vals_f, ptr_fT, cols_fT, vals_fT,
        xg_s, xg_c, c2s_w, c2s_b, s2c_w, s2c_b, xg2_s, xg2_c, cheb_nblk_s);
    gru_kernel<<<gru_grid, 256, 0, stream>>>(
        x_hist, features, xp_s, xg2_s, gru_wi, gru_wh, gru_bi, gru_bh, h_s, fc_w, fc_b,
        c_x_hist, c_features, xp_c, xg2_c, c_gru_wi, c_gru_wh, c_gru_bi, c_gru_bh, h_c, c_fc_w, c_fc_b,
        out, xp_s, xp_c, 1, t, TH + t, gru_nblk_s);
  }
}

// Round 4
// 7878.657 us; speedup vs baseline: 1.5604x; 1.5604x over previous
//
#include <hip/hip_runtime.h>
#include <hip/hip_cooperative_groups.h>
#include <math.h>

namespace cg = cooperative_groups;

#define B 8
#define NS 4096
#define NC 256
#define TH 8
#define TP 24
#define T_ALL 32
#define DIN 28
#define DM 27
#define G 64
#define H 64
#define DGRU 92
#define NG3 192
#define NSTEP 31

#define NBLK 512
#define NTHR 256
#define SROWS 64          // station nodes per block (32768/512)
#define CROWS 4           // city nodes per block   (2048/512)
#define ROWS 68
#define BUFW 65           // +1 pad: 4 rows/wave hit distinct banks

#define WS_ELL 64         // laplacian ELL width (station deg ~16 max<45, city ~26 max<50)
#define WF_ELL 32         // afc station rows (deg ~4, max<20)
#define WFT_ELL 128       // afc^T city rows (deg ~64, max<100)

struct Params {
  const float *x_hist, *feat_s, *c_x_hist, *feat_c, *adj_s, *adj_c, *afc;
  const float *conv_w, *conv_b, *c_conv_w, *c_conv_b;
  const float *gru_wi, *gru_wh, *gru_bi, *gru_bh;
  const float *c_gru_wi, *c_gru_wh, *c_gru_bi, *c_gru_bh;
  const float *fc_w, *fc_b, *c_fc_w, *c_fc_b;
  const float *c2s_w, *c2s_b, *s2c_w, *s2c_b;
  int *deg_s, *ellc_s; float *ellv_s, *dinv_s;
  int *deg_c, *ellc_c; float *ellv_c, *dinv_c;
  int *degf, *ellf;
  int *degfT, *ellfT;
  float *xg_s, *xg_c, *xp_s, *xp_c;
  float *h_s, *h_c;
  float *out;
};

__device__ __forceinline__ float sigm_(float x) { return 1.0f / (1.0f + expf(-x)); }

// x channel f of node n at global step. f==0: x_hist (hist) / xprev (pred);
// f>=1: features at time step+1 (identical formula for hist & pred).
__device__ __forceinline__ float xval(const Params& p, int sta, int hist, int step,
                                      int b, int n, int f) {
  if (f == 0) {
    if (hist) return sta ? p.x_hist[((size_t)b * TH + step) * NS + n]
                         : p.c_x_hist[((size_t)b * TH + step) * NC + n];
    return sta ? p.xp_s[b * NS + n] : p.xp_c[b * NC + n];
  }
  int tf = step + 1;
  return sta ? p.feat_s[(((size_t)b * T_ALL + tf) * NS + n) * DM + (f - 1)]
             : p.feat_c[(((size_t)b * T_ALL + tf) * NC + n) * DM + (f - 1)];
}

#define FMA12(acc, aval, wptr) do {                                        \
    float4 w0_ = *(const float4*)(wptr);                                   \
    float4 w1_ = *(const float4*)((wptr) + 64);                            \
    float4 w2_ = *(const float4*)((wptr) + 128);                           \
    acc[0] += (aval) * w0_.x; acc[1] += (aval) * w0_.y;                    \
    acc[2] += (aval) * w0_.z; acc[3] += (aval) * w0_.w;                    \
    acc[4] += (aval) * w1_.x; acc[5] += (aval) * w1_.y;                    \
    acc[6] += (aval) * w1_.z; acc[7] += (aval) * w1_.w;                    \
    acc[8] += (aval) * w2_.x; acc[9] += (aval) * w2_.y;                    \
    acc[10] += (aval) * w2_.z; acc[11] += (aval) * w2_.w;                  \
  } while (0)

// ---------------- table build: ELL via ballot compaction, one wave per row ----------------
__device__ void build_tables(const Params& p, int bid, int tid, int nblk) {
  const int lane = tid & 63;
  const int gw = bid * 4 + (tid >> 6);
  const int nw = nblk * 4;

  for (int r = gw; r < NS; r += nw) { // station laplacian
    int base = 0;
    for (int n0 = 0; n0 < NS; n0 += 64) {
      int n = n0 + lane;
      float v = p.adj_s[(size_t)r * NS + n];
      bool fl = (v != 0.0f) && (n != r);
      unsigned long long m = __ballot(fl);
      if (fl) {
        int pos = base + (int)__popcll(m & ((1ull << lane) - 1ull));
        if (pos < WS_ELL) p.ellc_s[r * WS_ELL + pos] = n;
      }
      base += (int)__popcll(m);
    }
    int deg = base < WS_ELL ? base : WS_ELL;
    for (int s = deg + lane; s < WS_ELL; s += 64) p.ellc_s[r * WS_ELL + s] = 0;
    if (lane == 0) {
      p.deg_s[r] = deg;
      p.dinv_s[r] = base > 0 ? 1.0f / sqrtf((float)base) : 0.0f;
    }
  }
  for (int r = gw; r < NS; r += nw) { // afc rows (binary -> cols only)
    int base = 0;
    for (int n0 = 0; n0 < NC; n0 += 64) {
      int n = n0 + lane;
      bool fl = p.afc[(size_t)r * NC + n] != 0.0f;
      unsigned long long m = __ballot(fl);
      if (fl) {
        int pos = base + (int)__popcll(m & ((1ull << lane) - 1ull));
        if (pos < WF_ELL) p.ellf[r * WF_ELL + pos] = n;
      }
      base += (int)__popcll(m);
    }
    int deg = base < WF_ELL ? base : WF_ELL;
    for (int s = deg + lane; s < WF_ELL; s += 64) p.ellf[r * WF_ELL + s] = 0;
    if (lane == 0) p.degf[r] = deg;
  }
  for (int r = gw; r < NC; r += nw) { // city laplacian
    int base = 0;
    for (int n0 = 0; n0 < NC; n0 += 64) {
      int n = n0 + lane;
      float v = p.adj_c[(size_t)r * NC + n];
      bool fl = (v != 0.0f) && (n != r);
      unsigned long long m = __ballot(fl);
      if (fl) {
        int pos = base + (int)__popcll(m & ((1ull << lane) - 1ull));
        if (pos < WS_ELL) p.ellc_c[r * WS_ELL + pos] = n;
      }
      base += (int)__popcll(m);
    }
    int deg = base < WS_ELL ? base : WS_ELL;
    for (int s = deg + lane; s < WS_ELL; s += 64) p.ellc_c[r * WS_ELL + s] = 0;
    if (lane == 0) {
      p.deg_c[r] = deg;
      p.dinv_c[r] = base > 0 ? 1.0f / sqrtf((float)base) : 0.0f;
    }
  }
  for (int r = gw; r < NC; r += nw) { // afc^T rows (scan column r of afc)
    int base = 0;
    for (int n0 = 0; n0 < NS; n0 += 64) {
      int n = n0 + lane;
      bool fl = p.afc[(size_t)n * NC + r] != 0.0f;
      unsigned long long m = __ballot(fl);
      if (fl) {
        int pos = base + (int)__popcll(m & ((1ull << lane) - 1ull));
        if (pos < WFT_ELL) p.ellfT[r * WFT_ELL + pos] = n;
      }
      base += (int)__popcll(m);
    }
    int deg = base < WFT_ELL ? base : WFT_ELL;
    for (int s = deg + lane; s < WFT_ELL; s += 64) p.ellfT[r * WFT_ELL + s] = 0;
    if (lane == 0) p.degfT[r] = deg;
  }
  // xprev init + h zero
  const int gid = bid * NTHR + tid, ntot = nblk * NTHR;
  for (int i = gid; i < B * NS; i += ntot)
    p.xp_s[i] = p.x_hist[((size_t)(i / NS) * TH + (TH - 1)) * NS + (i % NS)];
  for (int i = gid; i < B * NC; i += ntot)
    p.xp_c[i] = p.c_x_hist[((size_t)(i / NC) * TH + (TH - 1)) * NC + (i % NC)];
  for (int i = gid; i < B * NS * H; i += ntot) p.h_s[i] = 0.0f;
  for (int i = gid; i < B * NC * H; i += ntot) p.h_c[i] = 0.0f;
}

__device__ void ellv_fill(const Params& p, int gid, int ntot) {
  for (int s = gid; s < NS * WS_ELL; s += ntot) {
    int r = s >> 6, k = s & (WS_ELL - 1);
    p.ellv_s[s] = (k < p.deg_s[r]) ? -p.dinv_s[r] * p.dinv_s[p.ellc_s[s]] : 0.0f;
  }
  for (int s = gid; s < NC * WS_ELL; s += ntot) {
    int r = s >> 6, k = s & (WS_ELL - 1);
    p.ellv_c[s] = (k < p.deg_c[r]) ? -p.dinv_c[r] * p.dinv_c[p.ellc_c[s]] : 0.0f;
  }
}

// ---------------- phase A: cheb conv -> sigmoid -> global xg ----------------
__device__ __forceinline__ void phaseA(const Params& p, int bid, int tid, int hist, int step,
                                       float (*xa)[DIN], float (*buf)[BUFW]) {
  for (int q = tid; q < ROWS * DIN; q += NTHR) {
    int i = q / DIN, f = q % DIN;
    int sta = (i < SROWS);
    int b, n;
    const int* cc; const float* vv; int trip;
    if (sta) {
      int sm = bid * SROWS + i; b = sm >> 12; n = sm & 4095;
      cc = &p.ellc_s[n * WS_ELL]; vv = &p.ellv_s[n * WS_ELL];
      trip = (p.deg_s[n] + 3) & ~3;
    } else {
      int cm = bid * CROWS + (i - SROWS); b = cm >> 8; n = cm & 255;
      cc = &p.ellc_c[n * WS_ELL]; vv = &p.ellv_c[n * WS_ELL];
      trip = (p.deg_c[n] + 3) & ~3;
    }
    xa[i][f] = xval(p, sta, hist, step, b, n, f);
    float acc = 0.0f;
    for (int e = 0; e < trip; e += 4) {
      int c0 = cc[e], c1 = cc[e + 1], c2 = cc[e + 2], c3 = cc[e + 3];
      float v0 = vv[e], v1 = vv[e + 1], v2 = vv[e + 2], v3 = vv[e + 3];
      acc += v0 * xval(p, sta, hist, step, b, c0, f)
           + v1 * xval(p, sta, hist, step, b, c1, f)
           + v2 * xval(p, sta, hist, step, b, c2, f)
           + v3 * xval(p, sta, hist, step, b, c3, f);
    }
    buf[i][f] = acc;
  }
  __syncthreads();
  for (int q = tid; q < ROWS * G; q += NTHR) {
    int i = q >> 6, g = q & 63;
    int sta = (i < SROWS);
    const float* W = sta ? p.conv_w : p.c_conv_w;
    float acc = (sta ? p.conv_b : p.c_conv_b)[g];
#pragma unroll 4
    for (int f = 0; f < DIN; f++)
      acc += xa[i][f] * W[f * G + g] + buf[i][f] * W[DIN * G + f * G + g];
    float s = sigm_(acc);
    if (sta) p.xg_s[(size_t)(bid * SROWS + i) * G + g] = s;
    else     p.xg_c[(size_t)(bid * CROWS + (i - SROWS)) * G + g] = s;
  }
}

// ---------------- phase B: fuse + GRU (+ fc head in pred) ----------------
__device__ __forceinline__ void phaseB(const Params& p, int bid, int tid, int hist, int step,
                                       int idx, int need_xa,
                                       float (*xa)[DIN], float (*buf)[BUFW]) {
  if (need_xa) {
    for (int q = tid; q < ROWS * DIN; q += NTHR) {
      int i = q / DIN, f = q % DIN;
      int sta = (i < SROWS);
      int b, n;
      if (sta) { int sm = bid * SROWS + i; b = sm >> 12; n = sm & 4095; }
      else { int cm = bid * CROWS + (i - SROWS); b = cm >> 8; n = cm & 255; }
      xa[i][f] = xval(p, sta, hist, step, b, n, f);
    }
  }
  // B1 stations (deg~4): one thread per (i,g)
#pragma unroll
  for (int k = 0; k < (SROWS * G) / NTHR; k++) {   // 16
    int q = tid + k * NTHR;
    int i = q >> 6, g = q & 63;
    int sm = bid * SROWS + i; int b = sm >> 12; int r = sm & 4095;
    int dg = p.degf[r];
    const int* cc = &p.ellf[r * WF_ELL];
    size_t bb = (size_t)b * NC;
    float acc = 0.0f;
    int e = 0;
    for (; e + 4 <= dg; e += 4) {
      acc += p.xg_c[(bb + cc[e]) * G + g] + p.xg_c[(bb + cc[e + 1]) * G + g]
           + p.xg_c[(bb + cc[e + 2]) * G + g] + p.xg_c[(bb + cc[e + 3]) * G + g];
    }
    for (; e < dg; e++) acc += p.xg_c[(bb + cc[e]) * G + g];
    buf[i][g] = acc;
  }
  // B1 cities (deg~64-96): 4 threads per (i,g), quarter-split + width-4 shuffle reduce
  {
    int g = (tid >> 2) & 63;
    int quar = tid & 3;
#pragma unroll
    for (int ci = 0; ci < CROWS; ci++) {
      int i = SROWS + ci;
      int cm = bid * CROWS + ci; int b = cm >> 8; int r = cm & 255;
      int dg = p.degfT[r];
      const int* cc = &p.ellfT[r * WFT_ELL];
      int dq = (dg + 3) >> 2;
      int e0 = quar * dq;
      int e1 = e0 + dq; if (e1 > dg) e1 = dg; if (e0 > dg) e0 = dg;
      size_t bb = (size_t)b * NS;
      float acc = 0.0f;
      int e = e0;
      for (; e + 4 <= e1; e += 4) {
        acc += p.xg_s[(bb + cc[e]) * G + g] + p.xg_s[(bb + cc[e + 1]) * G + g]
             + p.xg_s[(bb + cc[e + 2]) * G + g] + p.xg_s[(bb + cc[e + 3]) * G + g];
      }
      for (; e < e1; e++) acc += p.xg_s[(bb + cc[e]) * G + g];
      acc += __shfl_down(acc, 2, 4);
      acc += __shfl_down(acc, 1, 4);
      if (quar == 0) buf[i][g] = acc;
    }
  }
  __syncthreads();

  // B2: fused = own_xg + gather@Wm + b (register-staged, then overwrite buf)
  {
    float fv[(ROWS * G) / NTHR];   // 17, exact
    int kk = 0;
    for (int q = tid; q < ROWS * G; q += NTHR, kk++) {
      int i = q >> 6, g = q & 63;
      int sta = (i < SROWS);
      const float* Wm = sta ? p.c2s_w : p.s2c_w;
      float acc = (sta ? p.c2s_b : p.s2c_b)[g];
#pragma unroll 4
      for (int f = 0; f < G; f++) acc += buf[i][f] * Wm[f * G + g];
      float own = sta ? p.xg_s[(size_t)(bid * SROWS + i) * G + g]
                      : p.xg_c[(size_t)(bid * CROWS + (i - SROWS)) * G + g];
      fv[kk] = own + acc;
    }
    __syncthreads();
    kk = 0;
    for (int q = tid; q < ROWS * G; q += NTHR, kk++) buf[q >> 6][q & 63] = fv[kk];
    __syncthreads();
  }

  // B3: GRU. 16 threads/node, 4 cols/gate each; h in global (float4/thread).
  const int sub = tid & 15;
  const int j0 = sub * 4;
  const int basel = (tid & 63) & ~15;
  for (int pass = 0; pass < (ROWS + 15) / 16; pass++) {   // 5
    int i = pass * 16 + (tid >> 4);
    if (i < ROWS) {
      int sta = (i < SROWS);
      float* hp;
      int b, n, sm = 0, cm = 0;
      if (sta) { sm = bid * SROWS + i; b = sm >> 12; n = sm & 4095; hp = p.h_s + (size_t)sm * H; }
      else { cm = bid * CROWS + (i - SROWS); b = cm >> 8; n = cm & 255; hp = p.h_c + (size_t)cm * H; }
      const float* wi = sta ? p.gru_wi : p.c_gru_wi;
      const float* wh = sta ? p.gru_wh : p.c_gru_wh;
      const float* bi = sta ? p.gru_bi : p.c_gru_bi;
      const float* bh = sta ? p.gru_bh : p.c_gru_bh;
      float4 hval = *(const float4*)(hp + j0);
      float aA[12], aB[12];
#pragma unroll
      for (int k = 0; k < 4; k++) {
        aA[k] = bi[j0 + k]; aA[4 + k] = bi[64 + j0 + k]; aA[8 + k] = bi[128 + j0 + k];
        aB[k] = bh[j0 + k]; aB[4 + k] = bh[64 + j0 + k]; aB[8 + k] = bh[128 + j0 + k];
      }
      for (int d = 0; d < DIN; d++) {
        float a = xa[i][d];
        FMA12(aA, a, wi + d * NG3 + j0);
      }
      for (int d = 0; d < G; d++) {
        float a = buf[i][d];
        FMA12(aA, a, wi + (DIN + d) * NG3 + j0);
      }
      for (int d0 = 0; d0 < H; d0 += 4) {
        int src = basel + (d0 >> 2);
        float a0 = __shfl(hval.x, src, 64);
        float a1 = __shfl(hval.y, src, 64);
        float a2 = __shfl(hval.z, src, 64);
        float a3 = __shfl(hval.w, src, 64);
        FMA12(aB, a0, wh + (d0 + 0) * NG3 + j0);
        FMA12(aB, a1, wh + (d0 + 1) * NG3 + j0);
        FMA12(aB, a2, wh + (d0 + 2) * NG3 + j0);
        FMA12(aB, a3, wh + (d0 + 3) * NG3 + j0);
      }
      int iv = 1 << (sub >> 2);           // cols j0..j0+3 share one 16-wide interval group
      int upd = ((idx & (iv - 1)) == 0);
      float ho[4] = {hval.x, hval.y, hval.z, hval.w};
      float hv[4];
#pragma unroll
      for (int k = 0; k < 4; k++) {
        float r = sigm_(aA[k] + aB[k]);
        float z = sigm_(aA[4 + k] + aB[4 + k]);
        float nn = tanhf(aA[8 + k] + r * aB[8 + k]);
        float hn = (1.0f - z) * nn + z * ho[k];
        hv[k] = upd ? hn : ho[k];
      }
      float4 hstore; hstore.x = hv[0]; hstore.y = hv[1]; hstore.z = hv[2]; hstore.w = hv[3];
      *(float4*)(hp + j0) = hstore;
      if (!hist) {
        const float* fw = sta ? p.fc_w : p.c_fc_w;
        float part = hv[0] * fw[j0] + hv[1] * fw[j0 + 1] +
                     hv[2] * fw[j0 + 2] + hv[3] * fw[j0 + 3];
        part += __shfl_down(part, 8, 16);
        part += __shfl_down(part, 4, 16);
        part += __shfl_down(part, 2, 16);
        part += __shfl_down(part, 1, 16);
        if (sub == 0) {
          int t = step - (TH - 1);
          if (sta) {
            float y = part + p.fc_b[0];
            p.out[((size_t)b * TP + t) * NS + n] = y;
            p.xp_s[sm] = y;
          } else {
            float y = part + p.c_fc_b[0];
            p.out[(size_t)B * TP * NS + ((size_t)b * TP + t) * NC + n] = y;
            p.xp_c[cm] = y;
          }
        }
      }
    }
  }
}

// ---------------- kernels ----------------
__global__ __launch_bounds__(NTHR, 2) void persist_kernel(Params p) {
  cg::grid_group grid = cg::this_grid();
  __shared__ float xa[ROWS][DIN];
  __shared__ float buf[ROWS][BUFW];
  build_tables(p, blockIdx.x, threadIdx.x, gridDim.x);
  grid.sync();
  ellv_fill(p, blockIdx.x * NTHR + threadIdx.x, gridDim.x * NTHR);
  grid.sync();
  for (int step = 0; step < NSTEP; step++) {
    int hist = (step < TH - 1) ? 1 : 0;
    phaseA(p, blockIdx.x, threadIdx.x, hist, step, xa, buf);
    grid.sync();
    phaseB(p, blockIdx.x, threadIdx.x, hist, step, step + 1, 0, xa, buf);
    grid.sync();
  }
}

__global__ __launch_bounds__(NTHR, 2) void build_kernel(Params p) {
  build_tables(p, blockIdx.x, threadIdx.x, gridDim.x);
}
__global__ __launch_bounds__(NTHR, 2) void ellv_kernel(Params p) {
  ellv_fill(p, blockIdx.x * NTHR + threadIdx.x, gridDim.x * NTHR);
}
__global__ __launch_bounds__(NTHR, 2) void stepA_kernel(Params p, int step, int hist) {
  __shared__ float xa[ROWS][DIN];
  __shared__ float buf[ROWS][BUFW];
  phaseA(p, blockIdx.x, threadIdx.x, hist, step, xa, buf);
}
__global__ __launch_bounds__(NTHR, 2) void stepB_kernel(Params p, int step, int hist, int idx) {
  __shared__ float xa[ROWS][DIN];
  __shared__ float buf[ROWS][BUFW];
  phaseB(p, blockIdx.x, threadIdx.x, hist, step, idx, 1, xa, buf);
}

extern "C" void kernel_launch(void* const* d_in, const int* in_sizes, int n_in,
                              void* d_out, int out_size, void* d_ws, size_t ws_size,
                              hipStream_t stream) {
  Params p;
  p.x_hist   = (const float*)d_in[0];
  p.feat_s   = (const float*)d_in[1];
  p.c_x_hist = (const float*)d_in[2];
  p.feat_c   = (const float*)d_in[3];
  p.adj_s    = (const float*)d_in[4];
  p.adj_c    = (const float*)d_in[5];
  p.afc      = (const float*)d_in[6];
  p.conv_w   = (const float*)d_in[7];
  p.conv_b   = (const float*)d_in[8];
  p.c_conv_w = (const float*)d_in[9];
  p.c_conv_b = (const float*)d_in[10];
  p.gru_wi   = (const float*)d_in[11];
  p.gru_wh   = (const float*)d_in[12];
  p.gru_bi   = (const float*)d_in[13];
  p.gru_bh   = (const float*)d_in[14];
  p.c_gru_wi = (const float*)d_in[15];
  p.c_gru_wh = (const float*)d_in[16];
  p.c_gru_bi = (const float*)d_in[17];
  p.c_gru_bh = (const float*)d_in[18];
  p.fc_w     = (const float*)d_in[19];
  p.fc_b     = (const float*)d_in[20];
  p.c_fc_w   = (const float*)d_in[21];
  p.c_fc_b   = (const float*)d_in[22];
  p.c2s_w    = (const float*)d_in[23];
  p.c2s_b    = (const float*)d_in[24];
  p.s2c_w    = (const float*)d_in[25];
  p.s2c_b    = (const float*)d_in[26];

  char* wp = (char*)d_ws;
  auto alloc = [&](size_t bytes) -> char* {
    char* q = wp;
    wp += (bytes + 255) & ~(size_t)255;
    return q;
  };
  p.deg_s  = (int*)alloc(NS * 4);
  p.dinv_s = (float*)alloc(NS * 4);
  p.ellc_s = (int*)alloc((size_t)NS * WS_ELL * 4);
  p.ellv_s = (float*)alloc((size_t)NS * WS_ELL * 4);
  p.deg_c  = (int*)alloc(NC * 4);
  p.dinv_c = (float*)alloc(NC * 4);
  p.ellc_c = (int*)alloc((size_t)NC * WS_ELL * 4);
  p.ellv_c = (float*)alloc((size_t)NC * WS_ELL * 4);
  p.degf   = (int*)alloc(NS * 4);
  p.ellf   = (int*)alloc((size_t)NS * WF_ELL * 4);
  p.degfT  = (int*)alloc(NC * 4);
  p.ellfT  = (int*)alloc((size_t)NC * WFT_ELL * 4);
  p.xg_s   = (float*)alloc((size_t)B * NS * G * 4);
  p.xg_c   = (float*)alloc((size_t)B * NC * G * 4);
  p.xp_s   = (float*)alloc((size_t)B * NS * 4);
  p.xp_c   = (float*)alloc((size_t)B * NC * 4);
  p.h_s    = (float*)alloc((size_t)B * NS * H * 4);
  p.h_c    = (float*)alloc((size_t)B * NC * H * 4);
  p.out    = (float*)d_out;

  // Decide launch mode (all queries are deterministic & graph-capture-safe).
  int dev = 0;
  hipGetDevice(&dev);
  int coopAttr = 0, numCU = 0, maxActive = 0;
  hipDeviceGetAttribute(&coopAttr, hipDeviceAttributeCooperativeLaunch, dev);
  hipDeviceGetAttribute(&numCU, hipDeviceAttributeMultiprocessorCount, dev);
  hipError_t oe = hipOccupancyMaxActiveBlocksPerMultiprocessor(
      &maxActive, (const void*)persist_kernel, NTHR, 0);

  hipError_t le = hipErrorUnknown;
  if (coopAttr && oe == hipSuccess && (long)maxActive * numCU >= NBLK) {
    void* kargs[] = { (void*)&p };
    le = hipLaunchCooperativeKernel((const void*)persist_kernel, dim3(NBLK), dim3(NTHR),
                                    kargs, 0, stream);
  }
  if (le != hipSuccess) {
    // Fallback: identical math, kernel-boundary synchronization (64 dispatches).
    build_kernel<<<NBLK, NTHR, 0, stream>>>(p);
    ellv_kernel<<<NBLK, NTHR, 0, stream>>>(p);
    for (int step = 0; step < NSTEP; step++) {
      int hist = (step < TH - 1) ? 1 : 0;
      stepA_kernel<<<NBLK, NTHR, 0, stream>>>(p, step, hist);
      stepB_kernel<<<NBLK, NTHR, 0, stream>>>(p, step, hist, step + 1);
    }
  }
}

// Round 5
// 6407.459 us; speedup vs baseline: 1.9186x; 1.2296x over previous
//
#include <hip/hip_runtime.h>
#include <hip/hip_cooperative_groups.h>
#include <math.h>

namespace cg = cooperative_groups;

typedef short bf16x8 __attribute__((ext_vector_type(8)));
typedef float f32x4 __attribute__((ext_vector_type(4)));

#define B 8
#define NS 4096
#define NC 256
#define TH 8
#define TP 24
#define T_ALL 32
#define DIN 28
#define DM 27
#define G 64
#define H 64
#define NG3 192
#define NSTEP 31

#define NBLK 512
#define NTHR 256
#define SROWS 64          // station rows per block
#define CROWS 4           // city rows per block
#define ROWS 68
#define BUFW 65
#define XCW 160           // xcat K width (92 x|xg + 64 h + 1 bias + 3 pad)
#define KIT 5             // K-iters of 32
#define NT 16             // N tiles (256 gate cols)
#define WFRAG (KIT*NT*64*8)   // 40960 bf16 per weight array

#define WS_ELL 64
#define WF_ELL 32
#define WFT_ELL 128

struct Params {
  const float *x_hist, *feat_s, *c_x_hist, *feat_c, *adj_s, *adj_c, *afc;
  const float *conv_w, *conv_b, *c_conv_w, *c_conv_b;
  const float *gru_wi, *gru_wh, *gru_bi, *gru_bh;
  const float *c_gru_wi, *c_gru_wh, *c_gru_bi, *c_gru_bh;
  const float *fc_w, *fc_b, *c_fc_w, *c_fc_b;
  const float *c2s_w, *c2s_b, *s2c_w, *s2c_b;
  int *deg_s, *ellc_s; float *ellv_s, *dinv_s;
  int *deg_c, *ellc_c; float *ellv_c, *dinv_c;
  int *degf, *ellf;
  int *degfT, *ellfT;
  float *xg_s, *xg_c, *xp_s, *xp_c;
  float *xcat;                       // [NBLK][ROWS][XCW] fp32
  unsigned short *wSh, *wSl, *wCh, *wCl;  // fragment-ordered Wcat bf16 hi/lo
  float *out;
};

struct Smem {
  union {
    struct { float xa[ROWS][DIN]; float lx[ROWS][DIN]; } a;
    float buf[ROWS][BUFW];
  } u;
  float cityfc[4][4];
};

__device__ __forceinline__ float sigm_(float x) { return 1.0f / (1.0f + expf(-x)); }

__device__ __forceinline__ unsigned short bf16rn(float f) {
  unsigned u = __float_as_uint(f);
  u += 0x7fffu + ((u >> 16) & 1u);
  return (unsigned short)(u >> 16);
}
__device__ __forceinline__ float bf16tof(unsigned short h) {
  return __uint_as_float(((unsigned)h) << 16);
}
__device__ __forceinline__ void split8(const float* a, bf16x8& hi, bf16x8& lo) {
#pragma unroll
  for (int j = 0; j < 8; j++) {
    unsigned short h = bf16rn(a[j]);
    hi[j] = (short)h;
    lo[j] = (short)bf16rn(a[j] - bf16tof(h));
  }
}

// Wcat[k][c]: rows 0..91 = wi, 92..155 = wh, 156 = bias, 157..159 = 0.
// cols 0..127 = r,z (x+h fused); 128..191 = xn (wi only); 192..255 = hc (wh only).
__device__ float wcat_val(int k, int c, const float* wi, const float* wh,
                          const float* bi, const float* bh) {
  if (k < 92)  { return (c < 192) ? wi[k * NG3 + c] : 0.0f; }
  if (k < 156) {
    int kk = k - 92;
    if (c < 128) return wh[kk * NG3 + c];
    if (c < 192) return 0.0f;
    return wh[kk * NG3 + (c - 64)];
  }
  if (k == 156) {
    if (c < 128) return bi[c] + bh[c];
    if (c < 192) return bi[c];
    return bh[c - 64];
  }
  return 0.0f;
}

// x channel f of node n at global step.
__device__ __forceinline__ float xval(const Params& p, int sta, int hist, int step,
                                      int b, int n, int f) {
  if (f == 0) {
    if (hist) return sta ? p.x_hist[((size_t)b * TH + step) * NS + n]
                         : p.c_x_hist[((size_t)b * TH + step) * NC + n];
    return sta ? p.xp_s[b * NS + n] : p.xp_c[b * NC + n];
  }
  int tf = step + 1;
  return sta ? p.feat_s[(((size_t)b * T_ALL + tf) * NS + n) * DM + (f - 1)]
             : p.feat_c[(((size_t)b * T_ALL + tf) * NC + n) * DM + (f - 1)];
}

// ---------------- P0: ELL tables + weight fragment prep + xcat init ----------------
__device__ void build_tables(const Params& p, int bid, int tid, int nblk) {
  const int lane = tid & 63;
  const int gw = bid * 4 + (tid >> 6);
  const int nw = nblk * 4;

  for (int r = gw; r < NS; r += nw) {
    int base = 0;
    for (int n0 = 0; n0 < NS; n0 += 64) {
      int n = n0 + lane;
      float v = p.adj_s[(size_t)r * NS + n];
      bool fl = (v != 0.0f) && (n != r);
      unsigned long long m = __ballot(fl);
      if (fl) {
        int pos = base + (int)__popcll(m & ((1ull << lane) - 1ull));
        if (pos < WS_ELL) p.ellc_s[r * WS_ELL + pos] = n;
      }
      base += (int)__popcll(m);
    }
    int deg = base < WS_ELL ? base : WS_ELL;
    for (int s = deg + lane; s < WS_ELL; s += 64) p.ellc_s[r * WS_ELL + s] = 0;
    if (lane == 0) {
      p.deg_s[r] = deg;
      p.dinv_s[r] = base > 0 ? 1.0f / sqrtf((float)base) : 0.0f;
    }
  }
  for (int r = gw; r < NS; r += nw) {
    int base = 0;
    for (int n0 = 0; n0 < NC; n0 += 64) {
      int n = n0 + lane;
      bool fl = p.afc[(size_t)r * NC + n] != 0.0f;
      unsigned long long m = __ballot(fl);
      if (fl) {
        int pos = base + (int)__popcll(m & ((1ull << lane) - 1ull));
        if (pos < WF_ELL) p.ellf[r * WF_ELL + pos] = n;
      }
      base += (int)__popcll(m);
    }
    int deg = base < WF_ELL ? base : WF_ELL;
    for (int s = deg + lane; s < WF_ELL; s += 64) p.ellf[r * WF_ELL + s] = 0;
    if (lane == 0) p.degf[r] = deg;
  }
  for (int r = gw; r < NC; r += nw) {
    int base = 0;
    for (int n0 = 0; n0 < NC; n0 += 64) {
      int n = n0 + lane;
      float v = p.adj_c[(size_t)r * NC + n];
      bool fl = (v != 0.0f) && (n != r);
      unsigned long long m = __ballot(fl);
      if (fl) {
        int pos = base + (int)__popcll(m & ((1ull << lane) - 1ull));
        if (pos < WS_ELL) p.ellc_c[r * WS_ELL + pos] = n;
      }
      base += (int)__popcll(m);
    }
    int deg = base < WS_ELL ? base : WS_ELL;
    for (int s = deg + lane; s < WS_ELL; s += 64) p.ellc_c[r * WS_ELL + s] = 0;
    if (lane == 0) {
      p.deg_c[r] = deg;
      p.dinv_c[r] = base > 0 ? 1.0f / sqrtf((float)base) : 0.0f;
    }
  }
  for (int r = gw; r < NC; r += nw) {
    int base = 0;
    for (int n0 = 0; n0 < NS; n0 += 64) {
      int n = n0 + lane;
      bool fl = p.afc[(size_t)n * NC + r] != 0.0f;
      unsigned long long m = __ballot(fl);
      if (fl) {
        int pos = base + (int)__popcll(m & ((1ull << lane) - 1ull));
        if (pos < WFT_ELL) p.ellfT[r * WFT_ELL + pos] = n;
      }
      base += (int)__popcll(m);
    }
    int deg = base < WFT_ELL ? base : WFT_ELL;
    for (int s = deg + lane; s < WFT_ELL; s += 64) p.ellfT[r * WFT_ELL + s] = 0;
    if (lane == 0) p.degfT[r] = deg;
  }

  const int gid = bid * NTHR + tid, ntot = nblk * NTHR;
  for (int i = gid; i < B * NS; i += ntot)
    p.xp_s[i] = p.x_hist[((size_t)(i / NS) * TH + (TH - 1)) * NS + (i % NS)];
  for (int i = gid; i < B * NC; i += ntot)
    p.xp_c[i] = p.c_x_hist[((size_t)(i / NC) * TH + (TH - 1)) * NC + (i % NC)];

  // weight fragments: u -> (kiter q, tile t, lane l, j); k = q*32 + (l>>4)*8 + j
  for (int u = gid; u < WFRAG; u += ntot) {
    int j = u & 7, l = (u >> 3) & 63, t = (u >> 9) & 15, q = u >> 13;
    int k = q * 32 + ((l >> 4) << 3) + j;
    int c = t * 16 + (l & 15);
    float ws = wcat_val(k, c, p.gru_wi, p.gru_wh, p.gru_bi, p.gru_bh);
    unsigned short hh = bf16rn(ws);
    p.wSh[u] = hh;
    p.wSl[u] = bf16rn(ws - bf16tof(hh));
    float wc = wcat_val(k, c, p.c_gru_wi, p.c_gru_wh, p.c_gru_bi, p.c_gru_bh);
    hh = bf16rn(wc);
    p.wCh[u] = hh;
    p.wCl[u] = bf16rn(wc - bf16tof(hh));
  }
  // xcat init: zeros, col 156 = 1.0 (bias row)
  for (int u = gid; u < NBLK * ROWS * XCW; u += ntot) {
    p.xcat[u] = ((u % XCW) == 156) ? 1.0f : 0.0f;
  }
}

__device__ void ellv_fill(const Params& p, int gid, int ntot) {
  for (int s = gid; s < NS * WS_ELL; s += ntot) {
    int r = s >> 6, k = s & (WS_ELL - 1);
    p.ellv_s[s] = (k < p.deg_s[r]) ? -p.dinv_s[r] * p.dinv_s[p.ellc_s[s]] : 0.0f;
  }
  for (int s = gid; s < NC * WS_ELL; s += ntot) {
    int r = s >> 6, k = s & (WS_ELL - 1);
    p.ellv_c[s] = (k < p.deg_c[r]) ? -p.dinv_c[r] * p.dinv_c[p.ellc_c[s]] : 0.0f;
  }
}

// ---------------- phase A: cheb conv -> sigmoid -> global xg (+ x into xcat) ----------------
__device__ __forceinline__ void phaseA(const Params& p, int bid, int tid, int hist, int step,
                                       Smem* sm) {
  float* xcb = p.xcat + (size_t)bid * (ROWS * XCW);
  for (int q = tid; q < ROWS * DIN; q += NTHR) {
    int i = q / DIN, f = q % DIN;
    int sta = (i < SROWS);
    int b, n;
    const int* cc; const float* vv; int trip;
    if (sta) {
      int smn = bid * SROWS + i; b = smn >> 12; n = smn & 4095;
      cc = &p.ellc_s[n * WS_ELL]; vv = &p.ellv_s[n * WS_ELL];
      trip = (p.deg_s[n] + 3) & ~3;
    } else {
      int cm = bid * CROWS + (i - SROWS); b = cm >> 8; n = cm & 255;
      cc = &p.ellc_c[n * WS_ELL]; vv = &p.ellv_c[n * WS_ELL];
      trip = (p.deg_c[n] + 3) & ~3;
    }
    float xv = xval(p, sta, hist, step, b, n, f);
    sm->u.a.xa[i][f] = xv;
    xcb[i * XCW + f] = xv;
    float acc = 0.0f;
    for (int e = 0; e < trip; e += 4) {
      int c0 = cc[e], c1 = cc[e + 1], c2 = cc[e + 2], c3 = cc[e + 3];
      float v0 = vv[e], v1 = vv[e + 1], v2 = vv[e + 2], v3 = vv[e + 3];
      acc += v0 * xval(p, sta, hist, step, b, c0, f)
           + v1 * xval(p, sta, hist, step, b, c1, f)
           + v2 * xval(p, sta, hist, step, b, c2, f)
           + v3 * xval(p, sta, hist, step, b, c3, f);
    }
    sm->u.a.lx[i][f] = acc;
  }
  __syncthreads();
  for (int q = tid; q < ROWS * G; q += NTHR) {
    int i = q >> 6, g = q & 63;
    int sta = (i < SROWS);
    const float* W = sta ? p.conv_w : p.c_conv_w;
    float acc = (sta ? p.conv_b : p.c_conv_b)[g];
#pragma unroll 4
    for (int f = 0; f < DIN; f++)
      acc += sm->u.a.xa[i][f] * W[f * G + g] + sm->u.a.lx[i][f] * W[DIN * G + f * G + g];
    float s = sigm_(acc);
    if (sta) p.xg_s[(size_t)(bid * SROWS + i) * G + g] = s;
    else     p.xg_c[(size_t)(bid * CROWS + (i - SROWS)) * G + g] = s;
  }
}

// ---------------- phase B: fuse + MFMA GRU GEMM + epilogue ----------------
__device__ __forceinline__ void phaseB(const Params& p, int bid, int tid, int hist, int step,
                                       int idx, Smem* sm) {
  float* xcb = p.xcat + (size_t)bid * (ROWS * XCW);
  // B1 stations (deg~4)
#pragma unroll
  for (int k = 0; k < (SROWS * G) / NTHR; k++) {
    int q = tid + k * NTHR;
    int i = q >> 6, g = q & 63;
    int smn = bid * SROWS + i; int b = smn >> 12; int r = smn & 4095;
    int dg = p.degf[r];
    const int* cc = &p.ellf[r * WF_ELL];
    size_t bb = (size_t)b * NC;
    float acc = 0.0f;
    int e = 0;
    for (; e + 4 <= dg; e += 4) {
      acc += p.xg_c[(bb + cc[e]) * G + g] + p.xg_c[(bb + cc[e + 1]) * G + g]
           + p.xg_c[(bb + cc[e + 2]) * G + g] + p.xg_c[(bb + cc[e + 3]) * G + g];
    }
    for (; e < dg; e++) acc += p.xg_c[(bb + cc[e]) * G + g];
    sm->u.buf[i][g] = acc;
  }
  // B1 cities (deg~64-96): 4 threads per (i,g)
  {
    int g = (tid >> 2) & 63;
    int quar = tid & 3;
#pragma unroll
    for (int ci = 0; ci < CROWS; ci++) {
      int i = SROWS + ci;
      int cm = bid * CROWS + ci; int b = cm >> 8; int r = cm & 255;
      int dg = p.degfT[r];
      const int* cc = &p.ellfT[r * WFT_ELL];
      int dq = (dg + 3) >> 2;
      int e0 = quar * dq;
      int e1 = e0 + dq; if (e1 > dg) e1 = dg; if (e0 > dg) e0 = dg;
      size_t bb = (size_t)b * NS;
      float acc = 0.0f;
      int e = e0;
      for (; e + 4 <= e1; e += 4) {
        acc += p.xg_s[(bb + cc[e]) * G + g] + p.xg_s[(bb + cc[e + 1]) * G + g]
             + p.xg_s[(bb + cc[e + 2]) * G + g] + p.xg_s[(bb + cc[e + 3]) * G + g];
      }
      for (; e < e1; e++) acc += p.xg_s[(bb + cc[e]) * G + g];
      acc += __shfl_down(acc, 2, 4);
      acc += __shfl_down(acc, 1, 4);
      if (quar == 0) sm->u.buf[i][g] = acc;
    }
  }
  __syncthreads();

  // B2: fused = own_xg + gather@Wm + b -> xcat cols 28..91
  for (int q = tid; q < ROWS * G; q += NTHR) {
    int i = q >> 6, g = q & 63;
    int sta = (i < SROWS);
    const float* Wm = sta ? p.c2s_w : p.s2c_w;
    float acc = (sta ? p.c2s_b : p.s2c_b)[g];
#pragma unroll 4
    for (int f = 0; f < G; f++) acc += sm->u.buf[i][f] * Wm[f * G + g];
    float own = sta ? p.xg_s[(size_t)(bid * SROWS + i) * G + g]
                    : p.xg_c[(size_t)(bid * CROWS + (i - SROWS)) * G + g];
    xcb[i * XCW + 28 + g] = own + acc;
  }
  __threadfence();
  __syncthreads();

  // B3: MFMA GEMM gates[80 x 256] = xcat[80 x 160] @ Wcat[160 x 256], bf16 3-term split
  const int l = tid & 63;
  const int wv = tid >> 6;
  f32x4 accS[NT];
  f32x4 accC[4];
#pragma unroll
  for (int t = 0; t < NT; t++) { accS[t][0] = 0.f; accS[t][1] = 0.f; accS[t][2] = 0.f; accS[t][3] = 0.f; }
#pragma unroll
  for (int t = 0; t < 4; t++) { accC[t][0] = 0.f; accC[t][1] = 0.f; accC[t][2] = 0.f; accC[t][3] = 0.f; }
  const bf16x8* WSh = (const bf16x8*)p.wSh;
  const bf16x8* WSl = (const bf16x8*)p.wSl;
  const bf16x8* WCh = (const bf16x8*)p.wCh;
  const bf16x8* WCl = (const bf16x8*)p.wCl;

  for (int q = 0; q < KIT; q++) {
    int kc = q * 32 + ((l >> 4) << 3);
    bf16x8 aSh, aSl, aCh, aCl;
    {
      float av[8];
      const float4* s4 = (const float4*)(xcb + (wv * 16 + (l & 15)) * XCW + kc);
      float4 v0 = s4[0], v1 = s4[1];
      av[0] = v0.x; av[1] = v0.y; av[2] = v0.z; av[3] = v0.w;
      av[4] = v1.x; av[5] = v1.y; av[6] = v1.z; av[7] = v1.w;
      split8(av, aSh, aSl);
    }
    if ((l & 15) < 4) {
      float av[8];
      const float4* s4 = (const float4*)(xcb + (SROWS + (l & 15)) * XCW + kc);
      float4 v0 = s4[0], v1 = s4[1];
      av[0] = v0.x; av[1] = v0.y; av[2] = v0.z; av[3] = v0.w;
      av[4] = v1.x; av[5] = v1.y; av[6] = v1.z; av[7] = v1.w;
      split8(av, aCh, aCl);
    } else {
#pragma unroll
      for (int j = 0; j < 8; j++) { aCh[j] = 0; aCl[j] = 0; }
    }
    int base = q * (NT * 64) + l;
#pragma unroll
    for (int t = 0; t < NT; t++) {
      bf16x8 wh_ = WSh[base + t * 64];
      bf16x8 wl_ = WSl[base + t * 64];
      accS[t] = __builtin_amdgcn_mfma_f32_16x16x32_bf16(aSh, wh_, accS[t], 0, 0, 0);
      accS[t] = __builtin_amdgcn_mfma_f32_16x16x32_bf16(aSl, wh_, accS[t], 0, 0, 0);
      accS[t] = __builtin_amdgcn_mfma_f32_16x16x32_bf16(aSh, wl_, accS[t], 0, 0, 0);
    }
#pragma unroll
    for (int tt = 0; tt < 4; tt++) {
      int t = wv + tt * 4;
      bf16x8 wh_ = WCh[base + t * 64];
      bf16x8 wl_ = WCl[base + t * 64];
      accC[tt] = __builtin_amdgcn_mfma_f32_16x16x32_bf16(aCh, wh_, accC[tt], 0, 0, 0);
      accC[tt] = __builtin_amdgcn_mfma_f32_16x16x32_bf16(aCl, wh_, accC[tt], 0, 0, 0);
      accC[tt] = __builtin_amdgcn_mfma_f32_16x16x32_bf16(aCh, wl_, accC[tt], 0, 0, 0);
    }
  }
  __syncthreads();   // all A-frag reads done before h is overwritten

  const int pred = !hist;
  const int t_out = step - (TH - 1);
  // station epilogue: C layout col=lane&15, row=(lane>>4)*4+reg
  {
    float fcacc[4] = {0.f, 0.f, 0.f, 0.f};
#pragma unroll
    for (int g = 0; g < 4; g++) {
      int j = g * 16 + (l & 15);
      int upd = ((idx & ((1 << g) - 1)) == 0);
      float fwj = p.fc_w[j];
#pragma unroll
      for (int r = 0; r < 4; r++) {
        int row = wv * 16 + ((l >> 4) << 2) + r;
        float rr = sigm_(accS[g][r]);
        float zz = sigm_(accS[4 + g][r]);
        float nn = tanhf(accS[8 + g][r] + rr * accS[12 + g][r]);
        float* hp = xcb + row * XCW + 92 + j;
        float ho = *hp;
        float hn = upd ? ((1.0f - zz) * nn + zz * ho) : ho;
        *hp = hn;
        fcacc[r] += fwj * hn;
      }
    }
    if (pred) {
#pragma unroll
      for (int r = 0; r < 4; r++) {
        float v = fcacc[r];
        v += __shfl_down(v, 8, 16);
        v += __shfl_down(v, 4, 16);
        v += __shfl_down(v, 2, 16);
        v += __shfl_down(v, 1, 16);
        if ((l & 15) == 0) {
          int row = wv * 16 + ((l >> 4) << 2) + r;
          int smn = bid * SROWS + row; int b = smn >> 12; int n = smn & 4095;
          float y = v + p.fc_b[0];
          p.out[((size_t)b * TP + t_out) * NS + n] = y;
          p.xp_s[smn] = y;
        }
      }
    }
  }
  // city epilogue: wave wv owns j in [wv*16, wv*16+16); rows 0..3 valid (lanes 0..15)
  {
    float cfc[4] = {0.f, 0.f, 0.f, 0.f};
    if ((l >> 4) == 0) {
      int j = wv * 16 + (l & 15);
      int upd = ((idx & ((1 << wv) - 1)) == 0);
      float fwj = p.c_fc_w[j];
#pragma unroll
      for (int r = 0; r < 4; r++) {
        float rr = sigm_(accC[0][r]);
        float zz = sigm_(accC[1][r]);
        float nn = tanhf(accC[2][r] + rr * accC[3][r]);
        float* hp = xcb + (SROWS + r) * XCW + 92 + j;
        float ho = *hp;
        float hn = upd ? ((1.0f - zz) * nn + zz * ho) : ho;
        *hp = hn;
        cfc[r] = fwj * hn;
      }
    }
    if (pred) {
#pragma unroll
      for (int r = 0; r < 4; r++) {
        float v = cfc[r];
        v += __shfl_down(v, 8, 16);
        v += __shfl_down(v, 4, 16);
        v += __shfl_down(v, 2, 16);
        v += __shfl_down(v, 1, 16);
        if (l == 0) sm->cityfc[wv][r] = v;
      }
      __syncthreads();
      if (tid < 4) {
        float y = sm->cityfc[0][tid] + sm->cityfc[1][tid] + sm->cityfc[2][tid] +
                  sm->cityfc[3][tid] + p.c_fc_b[0];
        int cm = bid * CROWS + tid; int b = cm >> 8; int n = cm & 255;
        p.out[(size_t)B * TP * NS + ((size_t)b * TP + t_out) * NC + n] = y;
        p.xp_c[cm] = y;
      }
    }
  }
}

// ---------------- kernels ----------------
__global__ __launch_bounds__(NTHR, 2) void persist_kernel(Params p) {
  cg::grid_group grid = cg::this_grid();
  __shared__ Smem sm;
  build_tables(p, blockIdx.x, threadIdx.x, gridDim.x);
  grid.sync();
  ellv_fill(p, blockIdx.x * NTHR + threadIdx.x, gridDim.x * NTHR);
  grid.sync();
  for (int step = 0; step < NSTEP; step++) {
    int hist = (step < TH - 1) ? 1 : 0;
    phaseA(p, blockIdx.x, threadIdx.x, hist, step, &sm);
    grid.sync();
    phaseB(p, blockIdx.x, threadIdx.x, hist, step, step + 1, &sm);
    grid.sync();
  }
}

__global__ __launch_bounds__(NTHR, 2) void build_kernel(Params p) {
  build_tables(p, blockIdx.x, threadIdx.x, gridDim.x);
}
__global__ __launch_bounds__(NTHR, 2) void ellv_kernel(Params p) {
  ellv_fill(p, blockIdx.x * NTHR + threadIdx.x, gridDim.x * NTHR);
}
__global__ __launch_bounds__(NTHR, 2) void stepA_kernel(Params p, int step, int hist) {
  __shared__ Smem sm;
  phaseA(p, blockIdx.x, threadIdx.x, hist, step, &sm);
}
__global__ __launch_bounds__(NTHR, 2) void stepB_kernel(Params p, int step, int hist, int idx) {
  __shared__ Smem sm;
  phaseB(p, blockIdx.x, threadIdx.x, hist, step, idx, &sm);
}

extern "C" void kernel_launch(void* const* d_in, const int* in_sizes, int n_in,
                              void* d_out, int out_size, void* d_ws, size_t ws_size,
                              hipStream_t stream) {
  Params p;
  p.x_hist   = (const float*)d_in[0];
  p.feat_s   = (const float*)d_in[1];
  p.c_x_hist = (const float*)d_in[2];
  p.feat_c   = (const float*)d_in[3];
  p.adj_s    = (const float*)d_in[4];
  p.adj_c    = (const float*)d_in[5];
  p.afc      = (const float*)d_in[6];
  p.conv_w   = (const float*)d_in[7];
  p.conv_b   = (const float*)d_in[8];
  p.c_conv_w = (const float*)d_in[9];
  p.c_conv_b = (const float*)d_in[10];
  p.gru_wi   = (const float*)d_in[11];
  p.gru_wh   = (const float*)d_in[12];
  p.gru_bi   = (const float*)d_in[13];
  p.gru_bh   = (const float*)d_in[14];
  p.c_gru_wi = (const float*)d_in[15];
  p.c_gru_wh = (const float*)d_in[16];
  p.c_gru_bi = (const float*)d_in[17];
  p.c_gru_bh = (const float*)d_in[18];
  p.fc_w     = (const float*)d_in[19];
  p.fc_b     = (const float*)d_in[20];
  p.c_fc_w   = (const float*)d_in[21];
  p.c_fc_b   = (const float*)d_in[22];
  p.c2s_w    = (const float*)d_in[23];
  p.c2s_b    = (const float*)d_in[24];
  p.s2c_w    = (const float*)d_in[25];
  p.s2c_b    = (const float*)d_in[26];

  char* wp = (char*)d_ws;
  auto alloc = [&](size_t bytes) -> char* {
    char* q = wp;
    wp += (bytes + 255) & ~(size_t)255;
    return q;
  };
  p.deg_s  = (int*)alloc(NS * 4);
  p.dinv_s = (float*)alloc(NS * 4);
  p.ellc_s = (int*)alloc((size_t)NS * WS_ELL * 4);
  p.ellv_s = (float*)alloc((size_t)NS * WS_ELL * 4);
  p.deg_c  = (int*)alloc(NC * 4);
  p.dinv_c = (float*)alloc(NC * 4);
  p.ellc_c = (int*)alloc((size_t)NC * WS_ELL * 4);
  p.ellv_c = (float*)alloc((size_t)NC * WS_ELL * 4);
  p.degf   = (int*)alloc(NS * 4);
  p.ellf   = (int*)alloc((size_t)NS * WF_ELL * 4);
  p.degfT  = (int*)alloc(NC * 4);
  p.ellfT  = (int*)alloc((size_t)NC * WFT_ELL * 4);
  p.xg_s   = (float*)alloc((size_t)B * NS * G * 4);
  p.xg_c   = (float*)alloc((size_t)B * NC * G * 4);
  p.xp_s   = (float*)alloc((size_t)B * NS * 4);
  p.xp_c   = (float*)alloc((size_t)B * NC * 4);
  p.xcat   = (float*)alloc((size_t)NBLK * ROWS * XCW * 4);
  p.wSh    = (unsigned short*)alloc((size_t)WFRAG * 2);
  p.wSl    = (unsigned short*)alloc((size_t)WFRAG * 2);
  p.wCh    = (unsigned short*)alloc((size_t)WFRAG * 2);
  p.wCl    = (unsigned short*)alloc((size_t)WFRAG * 2);
  p.out    = (float*)d_out;

  int dev = 0;
  hipGetDevice(&dev);
  int coopAttr = 0, numCU = 0, maxActive = 0;
  hipDeviceGetAttribute(&coopAttr, hipDeviceAttributeCooperativeLaunch, dev);
  hipDeviceGetAttribute(&numCU, hipDeviceAttributeMultiprocessorCount, dev);
  hipError_t oe = hipOccupancyMaxActiveBlocksPerMultiprocessor(
      &maxActive, (const void*)persist_kernel, NTHR, 0);

  hipError_t le = hipErrorUnknown;
  if (coopAttr && oe == hipSuccess && (long)maxActive * numCU >= NBLK) {
    void* kargs[] = { (void*)&p };
    le = hipLaunchCooperativeKernel((const void*)persist_kernel, dim3(NBLK), dim3(NTHR),
                                    kargs, 0, stream);
  }
  if (le != hipSuccess) {
    build_kernel<<<NBLK, NTHR, 0, stream>>>(p);
    ellv_kernel<<<NBLK, NTHR, 0, stream>>>(p);
    for (int step = 0; step < NSTEP; step++) {
      int hist = (step < TH - 1) ? 1 : 0;
      stepA_kernel<<<NBLK, NTHR, 0, stream>>>(p, step, hist);
      stepB_kernel<<<NBLK, NTHR, 0, stream>>>(p, step, hist, step + 1);
    }
  }
}